// Round 6
// baseline (454.387 us; speedup 1.0000x reference)
//
#include <hip/hip_runtime.h>
#include <math.h>

#define IMG_H 512
#define IMG_W 512
#define KW 11
#define RAD 5
#define T 8                 // output rows per thread
#define NG (IMG_W / 4)      // 128 float4 column-groups per row
#define NROWS (T + 2 * RAD) // 18 input rows per thread

#define C1F (0.01f * 0.01f)
#define C2F (0.03f * 0.03f)

struct RowBuf {
    float fa[20];
    float fb[20];
};

__device__ __forceinline__ float ssim_px(float mu1, float mu2, float sp) {
    float m12 = mu1 * mu2;
    float sigma = sp - m12;
    float sq = mu1 * mu1 + mu2 * mu2;
    return ((2.f * m12 + C1F) * (2.f * sigma + C2F)) / ((sq + C1F) * (sq + C2F));
}

// Hand-pipelined tile: iteration i prefetches row i+1's loads, then computes
// row i; sched_barrier(0) pins the stage boundaries so the compiler neither
// sinks the prefetch (round-3 latency exposure) nor hoists all 18 rows
// (round-5 spill explosion). Live set: 2 row bufs (80) + 96 acc ≈ 220 VGPR.
template <bool GUARD>
__device__ __forceinline__ void run_tile(const float* __restrict__ Ai,
                                         const float* __restrict__ Bi,
                                         int ybase, int g, const float* w,
                                         float4 (&accA)[T], float4 (&accB)[T],
                                         float4 (&accP)[T]) {
    RowBuf buf0, buf1;

    auto load_row = [&](int i, RowBuf& b) {
        int gy = ybase + i - RAD;
        bool rowok = true;
        if (GUARD) rowok = ((unsigned)gy < (unsigned)IMG_H);  // wave-uniform
        const float* rowA = Ai + (size_t)gy * IMG_W;
        const float* rowB = Bi + (size_t)gy * IMG_W;
#pragma unroll
        for (int m = 0; m < 5; ++m) {
            int gm = g + m - 2;
            float4 va = make_float4(0.f, 0.f, 0.f, 0.f);
            float4 vb = va;
            bool ok = rowok && ((unsigned)gm < (unsigned)NG);
            if (ok) {
                va = *(const float4*)(rowA + 4 * gm);
                vb = *(const float4*)(rowB + 4 * gm);
            }
            b.fa[4 * m] = va.x; b.fa[4 * m + 1] = va.y;
            b.fa[4 * m + 2] = va.z; b.fa[4 * m + 3] = va.w;
            b.fb[4 * m] = vb.x; b.fb[4 * m + 1] = vb.y;
            b.fb[4 * m + 2] = vb.z; b.fb[4 * m + 3] = vb.w;
        }
    };

    auto compute_row = [&](int i, RowBuf& b) {
        // Products once per row (bit-identical to computing inside the k-loop).
        float fp[20];
#pragma unroll
        for (int j = 0; j < 20; ++j) fp[j] = b.fa[j] * b.fb[j];

        float4 hA = make_float4(0.f, 0.f, 0.f, 0.f);
        float4 hB = hA, hP = hA;
#pragma unroll
        for (int k = 0; k < KW; ++k) {
            float wk = w[k];
            hA.x += wk * b.fa[3 + k];  hA.y += wk * b.fa[4 + k];
            hA.z += wk * b.fa[5 + k];  hA.w += wk * b.fa[6 + k];
            hB.x += wk * b.fb[3 + k];  hB.y += wk * b.fb[4 + k];
            hB.z += wk * b.fb[5 + k];  hB.w += wk * b.fb[6 + k];
            hP.x += wk * fp[3 + k];    hP.y += wk * fp[4 + k];
            hP.z += wk * fp[5 + k];    hP.w += wk * fp[6 + k];
        }

        // Vertical scatter: output o gets weight w[i-o] when 0 <= i-o <= 10.
#pragma unroll
        for (int o = 0; o < T; ++o) {
            if (i - o >= 0 && i - o < KW) {   // folds (i compile-time)
                float wk = w[i - o];
                accA[o].x += wk * hA.x; accA[o].y += wk * hA.y;
                accA[o].z += wk * hA.z; accA[o].w += wk * hA.w;
                accB[o].x += wk * hB.x; accB[o].y += wk * hB.y;
                accB[o].z += wk * hB.z; accB[o].w += wk * hB.w;
                accP[o].x += wk * hP.x; accP[o].y += wk * hP.y;
                accP[o].z += wk * hP.z; accP[o].w += wk * hP.w;
            }
        }
    };

    load_row(0, buf0);
#pragma unroll
    for (int i = 0; i < NROWS; ++i) {
        if (i + 1 < NROWS) {
            if (i & 1) load_row(i + 1, buf0);
            else       load_row(i + 1, buf1);
        }
        __builtin_amdgcn_sched_barrier(0);
        if (i & 1) compute_row(i, buf1);
        else       compute_row(i, buf0);
        __builtin_amdgcn_sched_barrier(0);
    }
}

// Each thread: 4 cols (one float4 group) x 8 output rows, all in registers.
// Block: 256 threads = 128 col-groups x 2 row-chunks -> 512 wide x 16 rows.
// Single launch: rb in {0,31} takes the guarded body (wave-uniform select).
// NOTE (round 4): capping VGPR below the ~220 live set spills accumulators
// -> GB-scale scratch traffic. Keep __launch_bounds__(256,2) (256-VGPR cap).
__global__ __launch_bounds__(256, 2)
void ssim_fused_kernel(const float* __restrict__ A, const float* __restrict__ B,
                       float* __restrict__ out, float inv_total) {
    __shared__ float wpart[4];

    const int tid = threadIdx.x;
    const int g = tid & (NG - 1);        // col-group 0..127
    const int rchunk = tid >> 7;         // 0..1 (wave-uniform)
    const int img = blockIdx.y;
    const int rb = blockIdx.x;           // 0..31
    const int ybase = rb * (2 * T) + rchunk * T;

    // Gaussian weights (sigma=1.5, K=11) — fp32 recipe matches np bit-exactly
    // (absmax 0.0 rounds 1-5). Pinned to SGPRs (wave-uniform).
    float w[KW];
    {
        float s = 0.f;
#pragma unroll
        for (int i = 0; i < KW; ++i) {
            float d = (float)(i - RAD);
            w[i] = expf(-(d * d) / 4.5f);
            s += w[i];
        }
        float inv = 1.0f / s;
#pragma unroll
        for (int i = 0; i < KW; ++i) {
            w[i] *= inv;
            w[i] = __int_as_float(__builtin_amdgcn_readfirstlane(__float_as_int(w[i])));
        }
    }

    const float* __restrict__ Ai = A + (size_t)img * IMG_H * IMG_W;
    const float* __restrict__ Bi = B + (size_t)img * IMG_H * IMG_W;

    float4 accA[T], accB[T], accP[T];
#pragma unroll
    for (int o = 0; o < T; ++o) {
        accA[o] = make_float4(0.f, 0.f, 0.f, 0.f);
        accB[o] = accA[o];
        accP[o] = accA[o];
    }

    if (rb == 0 || rb == 31) {
        run_tile<true>(Ai, Bi, ybase, g, w, accA, accB, accP);
    } else {
        run_tile<false>(Ai, Bi, ybase, g, w, accA, accB, accP);
    }

    // SSIM formula per pixel + per-thread accumulate (32 px/thread).
    float acc = 0.f;
#pragma unroll
    for (int o = 0; o < T; ++o) {
        acc += ssim_px(accA[o].x, accB[o].x, accP[o].x);
        acc += ssim_px(accA[o].y, accB[o].y, accP[o].y);
        acc += ssim_px(accA[o].z, accB[o].z, accP[o].z);
        acc += ssim_px(accA[o].w, accB[o].w, accP[o].w);
    }

    // Reduce: wave shuffle -> LDS -> one atomic per block.
#pragma unroll
    for (int off = 32; off > 0; off >>= 1)
        acc += __shfl_down(acc, off, 64);
    int wid = tid >> 6;
    int lane = tid & 63;
    if (lane == 0) wpart[wid] = acc;
    __syncthreads();
    if (tid == 0) {
        float s = (wpart[0] + wpart[1]) + (wpart[2] + wpart[3]);
        atomicAdd(out, s * inv_total);
    }
}

extern "C" void kernel_launch(void* const* d_in, const int* in_sizes, int n_in,
                              void* d_out, int out_size, void* d_ws, size_t ws_size,
                              hipStream_t stream) {
    const float* A = (const float*)d_in[0];
    const float* B = (const float*)d_in[1];
    float* out = (float*)d_out;

    const int total = in_sizes[0];                 // 32*1*512*512
    const int nimg = total / (IMG_H * IMG_W);      // 32

    hipMemsetAsync(d_out, 0, sizeof(float), stream);

    dim3 grid(IMG_H / (2 * T), nimg);              // (32, 32) — single launch
    ssim_fused_kernel<<<grid, 256, 0, stream>>>(A, B, out, 1.0f / (float)total);
}

// Round 7
// 258.961 us; speedup vs baseline: 1.7547x; 1.7547x over previous
//
#include <hip/hip_runtime.h>
#include <math.h>

#define IMG_H 512
#define IMG_W 512
#define KW 11
#define RAD 5
#define T 8                 // output rows per thread
#define NG (IMG_W / 4)      // 128 float4 column-groups per row
#define NROWS (T + 2 * RAD) // 18 input rows per thread

#define C1F (0.01f * 0.01f)
#define C2F (0.03f * 0.03f)

struct RowBuf {
    float fa[20];
    float fb[20];
};

__device__ __forceinline__ float ssim_px(float mu1, float mu2, float sp) {
    float m12 = mu1 * mu2;
    float sigma = sp - m12;
    float sq = mu1 * mu1 + mu2 * mu2;
    return ((2.f * m12 + C1F) * (2.f * sigma + C2F)) / ((sq + C1F) * (sq + C2F));
}

// Hand-pipelined tile, round-7 scheduling contract:
//  - sched_barrier(0x7) at the top of every row iteration: ALU may cross,
//    VMEM may NOT -> each row's 10 loads are confined between consecutive
//    barriers => exactly 1-row load lookahead (bounds the live set; r5's
//    unbounded hoist spilled), while VALU still schedules freely across
//    rows (r6's sched_barrier(0) forbade that and spilled worse).
//  - Live set ~210 VGPR: needs the 256-reg budget => __launch_bounds__(256,1)
//    (empirical gfx950 law from r4/r5/r6: budget = 256 / min_waves_arg).
template <bool GUARD>
__device__ __forceinline__ void run_tile(const float* __restrict__ Ai,
                                         const float* __restrict__ Bi,
                                         int ybase, int g, const float* w,
                                         float4 (&accA)[T], float4 (&accB)[T],
                                         float4 (&accP)[T]) {
    RowBuf buf0, buf1;

    auto load_row = [&](int i, RowBuf& b) {
        int gy = ybase + i - RAD;
        bool rowok = true;
        if (GUARD) rowok = ((unsigned)gy < (unsigned)IMG_H);  // wave-uniform
        const float* rowA = Ai + (size_t)gy * IMG_W;
        const float* rowB = Bi + (size_t)gy * IMG_W;
#pragma unroll
        for (int m = 0; m < 5; ++m) {
            int gm = g + m - 2;
            float4 va = make_float4(0.f, 0.f, 0.f, 0.f);
            float4 vb = va;
            bool ok = rowok && ((unsigned)gm < (unsigned)NG);
            if (ok) {
                va = *(const float4*)(rowA + 4 * gm);
                vb = *(const float4*)(rowB + 4 * gm);
            }
            b.fa[4 * m] = va.x; b.fa[4 * m + 1] = va.y;
            b.fa[4 * m + 2] = va.z; b.fa[4 * m + 3] = va.w;
            b.fb[4 * m] = vb.x; b.fb[4 * m + 1] = vb.y;
            b.fb[4 * m + 2] = vb.z; b.fb[4 * m + 3] = vb.w;
        }
    };

    auto compute_row = [&](int i, RowBuf& b) {
        // Products once per row (bit-identical to computing inside the k-loop).
        float fp[20];
#pragma unroll
        for (int j = 0; j < 20; ++j) fp[j] = b.fa[j] * b.fb[j];

        float4 hA = make_float4(0.f, 0.f, 0.f, 0.f);
        float4 hB = hA, hP = hA;
#pragma unroll
        for (int k = 0; k < KW; ++k) {
            float wk = w[k];
            hA.x += wk * b.fa[3 + k];  hA.y += wk * b.fa[4 + k];
            hA.z += wk * b.fa[5 + k];  hA.w += wk * b.fa[6 + k];
            hB.x += wk * b.fb[3 + k];  hB.y += wk * b.fb[4 + k];
            hB.z += wk * b.fb[5 + k];  hB.w += wk * b.fb[6 + k];
            hP.x += wk * fp[3 + k];    hP.y += wk * fp[4 + k];
            hP.z += wk * fp[5 + k];    hP.w += wk * fp[6 + k];
        }

        // Vertical scatter: output o gets weight w[i-o] when 0 <= i-o <= 10.
#pragma unroll
        for (int o = 0; o < T; ++o) {
            if (i - o >= 0 && i - o < KW) {   // folds (i compile-time)
                float wk = w[i - o];
                accA[o].x += wk * hA.x; accA[o].y += wk * hA.y;
                accA[o].z += wk * hA.z; accA[o].w += wk * hA.w;
                accB[o].x += wk * hB.x; accB[o].y += wk * hB.y;
                accB[o].z += wk * hB.z; accB[o].w += wk * hB.w;
                accP[o].x += wk * hP.x; accP[o].y += wk * hP.y;
                accP[o].z += wk * hP.z; accP[o].w += wk * hP.w;
            }
        }
    };

    load_row(0, buf0);
#pragma unroll
    for (int i = 0; i < NROWS; ++i) {
        // VMEM may not cross; ALU may. Bounds load lookahead to one row.
        __builtin_amdgcn_sched_barrier(0x7);
        if (i + 1 < NROWS) {
            if (i & 1) load_row(i + 1, buf0);
            else       load_row(i + 1, buf1);
        }
        if (i & 1) compute_row(i, buf1);
        else       compute_row(i, buf0);
    }
}

// Each thread: 4 cols (one float4 group) x 8 output rows, all in registers.
// Block: 256 threads = 128 col-groups x 2 row-chunks -> 512 wide x 16 rows.
// Single launch: rb in {0,31} takes the guarded body (wave-uniform select).
// NOTE (r4/r5/r6): VGPR budget = 256 / launch_bounds-arg on gfx950; anything
// below the ~210-reg live set spills accumulators -> GB-scale scratch.
__global__ __launch_bounds__(256, 1)
void ssim_fused_kernel(const float* __restrict__ A, const float* __restrict__ B,
                       float* __restrict__ out, float inv_total) {
    __shared__ float wpart[4];

    const int tid = threadIdx.x;
    const int g = tid & (NG - 1);        // col-group 0..127
    const int rchunk = tid >> 7;         // 0..1 (wave-uniform)
    const int img = blockIdx.y;
    const int rb = blockIdx.x;           // 0..31
    const int ybase = rb * (2 * T) + rchunk * T;

    // Gaussian weights (sigma=1.5, K=11) — fp32 recipe matches np bit-exactly
    // (absmax 0.0 rounds 1-6). Pinned to SGPRs (wave-uniform).
    float w[KW];
    {
        float s = 0.f;
#pragma unroll
        for (int i = 0; i < KW; ++i) {
            float d = (float)(i - RAD);
            w[i] = expf(-(d * d) / 4.5f);
            s += w[i];
        }
        float inv = 1.0f / s;
#pragma unroll
        for (int i = 0; i < KW; ++i) {
            w[i] *= inv;
            w[i] = __int_as_float(__builtin_amdgcn_readfirstlane(__float_as_int(w[i])));
        }
    }

    const float* __restrict__ Ai = A + (size_t)img * IMG_H * IMG_W;
    const float* __restrict__ Bi = B + (size_t)img * IMG_H * IMG_W;

    float4 accA[T], accB[T], accP[T];
#pragma unroll
    for (int o = 0; o < T; ++o) {
        accA[o] = make_float4(0.f, 0.f, 0.f, 0.f);
        accB[o] = accA[o];
        accP[o] = accA[o];
    }

    if (rb == 0 || rb == 31) {
        run_tile<true>(Ai, Bi, ybase, g, w, accA, accB, accP);
    } else {
        run_tile<false>(Ai, Bi, ybase, g, w, accA, accB, accP);
    }

    // SSIM formula per pixel + per-thread accumulate (32 px/thread).
    float acc = 0.f;
#pragma unroll
    for (int o = 0; o < T; ++o) {
        acc += ssim_px(accA[o].x, accB[o].x, accP[o].x);
        acc += ssim_px(accA[o].y, accB[o].y, accP[o].y);
        acc += ssim_px(accA[o].z, accB[o].z, accP[o].z);
        acc += ssim_px(accA[o].w, accB[o].w, accP[o].w);
    }

    // Reduce: wave shuffle -> LDS -> one atomic per block.
#pragma unroll
    for (int off = 32; off > 0; off >>= 1)
        acc += __shfl_down(acc, off, 64);
    int wid = tid >> 6;
    int lane = tid & 63;
    if (lane == 0) wpart[wid] = acc;
    __syncthreads();
    if (tid == 0) {
        float s = (wpart[0] + wpart[1]) + (wpart[2] + wpart[3]);
        atomicAdd(out, s * inv_total);
    }
}

extern "C" void kernel_launch(void* const* d_in, const int* in_sizes, int n_in,
                              void* d_out, int out_size, void* d_ws, size_t ws_size,
                              hipStream_t stream) {
    const float* A = (const float*)d_in[0];
    const float* B = (const float*)d_in[1];
    float* out = (float*)d_out;

    const int total = in_sizes[0];                 // 32*1*512*512
    const int nimg = total / (IMG_H * IMG_W);      // 32

    hipMemsetAsync(d_out, 0, sizeof(float), stream);

    dim3 grid(IMG_H / (2 * T), nimg);              // (32, 32) — single launch
    ssim_fused_kernel<<<grid, 256, 0, stream>>>(A, B, out, 1.0f / (float)total);
}

// Round 8
// 197.358 us; speedup vs baseline: 2.3024x; 1.3121x over previous
//
#include <hip/hip_runtime.h>
#include <math.h>

#define IMG_H 512
#define IMG_W 512
#define KW 11
#define RAD 5
#define TW 64               // output tile width
#define TH 16               // output tile height
#define VW 20               // float4 groups per staged row (80 floats: bx*64-8 .. +72)
#define SR (TH + 2 * RAD)   // 26 staged input rows
#define VSTR 21             // LDS stride in float4 (21*16B=336B = 84 banks = 20 mod 32)

#define C1F (0.01f * 0.01f)
#define C2F (0.03f * 0.03f)

// Round-8 structure: fully-LDS-staged two-pass. The r3..r7 register-accumulator
// design needs >256 live VGPRs and always spills (r7: VGPR=256 + 186MB scratch).
// Here no value lives across a phase boundary -> VGPR bounded ~100 by design.
// Phase 1 is a pure copy (independent loads, deep MLP across 16 waves/CU) so
// HBM latency pipelines; phases 2/3 read LDS only (~12cyc/b128 throughput).
__global__ __launch_bounds__(256)
void ssim_fused_kernel(const float* __restrict__ A, const float* __restrict__ B,
                       float* __restrict__ out, float inv_total) {
    __shared__ float4 sA4[SR][VSTR];   // staged raw A (26 x 20 used)
    __shared__ float4 sB4[SR][VSTR];
    __shared__ float4 vA4[TH][VSTR];   // vertical-conv intermediates (16 x 20)
    __shared__ float4 vB4[TH][VSTR];
    __shared__ float4 vP4[TH][VSTR];
    __shared__ float wpart[4];
    // total LDS = (2*26 + 3*16) * 21 * 16 = 33.6 KB -> 4 blocks/CU (16 waves/CU)

    const int tid = threadIdx.x;
    const int bx = blockIdx.x;   // 0..7
    const int by = blockIdx.y;   // 0..31
    const int img = blockIdx.z;

    // Gaussian weights (sigma=1.5, K=11) — fp32 recipe, absmax 0.0 rounds 1-7.
    float w[KW];
    {
        float s = 0.f;
#pragma unroll
        for (int i = 0; i < KW; ++i) {
            float d = (float)(i - RAD);
            w[i] = expf(-(d * d) / 4.5f);
            s += w[i];
        }
        float inv = 1.0f / s;
#pragma unroll
        for (int i = 0; i < KW; ++i) {
            w[i] *= inv;
            w[i] = __int_as_float(__builtin_amdgcn_readfirstlane(__float_as_int(w[i])));
        }
    }

    const float* __restrict__ Ai = A + (size_t)img * IMG_H * IMG_W;
    const float* __restrict__ Bi = B + (size_t)img * IMG_H * IMG_W;
    const int basex = bx * TW - 8;          // 16B-aligned (covers -5..+68 halo)
    const int ybase = by * TH - RAD;

    // ---- Phase 1: stage raw A,B rows into LDS (pure copy, coalesced) ----
    // 26*20 = 520 items; ~2 iters/thread; zero-fill outside image (conv pad).
    for (int idx = tid; idx < SR * VW; idx += 256) {
        int r = idx / VW;
        int c = idx - r * VW;
        int gx = basex + 4 * c;             // whole-float4 in/out (512%4==0)
        int gy = ybase + r;
        float4 a = make_float4(0.f, 0.f, 0.f, 0.f);
        float4 b = a;
        if ((unsigned)gy < (unsigned)IMG_H && (unsigned)gx < (unsigned)IMG_W) {
            size_t off = (size_t)gy * IMG_W + gx;
            a = *(const float4*)(Ai + off);
            b = *(const float4*)(Bi + off);
        }
        sA4[r][c] = a;
        sB4[r][c] = b;
    }
    __syncthreads();

    // ---- Phase 2: vertical 11-tap conv from LDS; P = A*B on the fly ----
    // 16*20 = 320 items; r = idx&15 so consecutive lanes hit different rows
    // (row stride 21 float4 -> <=2-way bank aliasing, free).
    for (int idx = tid; idx < TH * VW; idx += 256) {
        int r = idx & 15;
        int c = idx >> 4;
        float4 a = make_float4(0.f, 0.f, 0.f, 0.f);
        float4 b = a, p = a;
#pragma unroll
        for (int k = 0; k < KW; ++k) {
            float4 av = sA4[r + k][c];
            float4 bv = sB4[r + k][c];
            float wk = w[k];
            a.x += wk * av.x; a.y += wk * av.y; a.z += wk * av.z; a.w += wk * av.w;
            b.x += wk * bv.x; b.y += wk * bv.y; b.z += wk * bv.z; b.w += wk * bv.w;
            p.x += wk * (av.x * bv.x); p.y += wk * (av.y * bv.y);
            p.z += wk * (av.z * bv.z); p.w += wk * (av.w * bv.w);
        }
        vA4[r][c] = a;
        vB4[r][c] = b;
        vP4[r][c] = p;
    }
    __syncthreads();

    // ---- Phase 3: horizontal 11-tap conv + SSIM formula (1 item/thread) ----
    float acc = 0.f;
    {
        int r = tid >> 4;                   // 0..15
        int j = tid & 15;                   // output cols 4j..4j+3
        float fa[20], fb[20], fp[20];
#pragma unroll
        for (int m = 0; m < 5; ++m) {
            float4 t = vA4[r][j + m];
            fa[4 * m] = t.x; fa[4 * m + 1] = t.y; fa[4 * m + 2] = t.z; fa[4 * m + 3] = t.w;
        }
#pragma unroll
        for (int m = 0; m < 5; ++m) {
            float4 t = vB4[r][j + m];
            fb[4 * m] = t.x; fb[4 * m + 1] = t.y; fb[4 * m + 2] = t.z; fb[4 * m + 3] = t.w;
        }
#pragma unroll
        for (int m = 0; m < 5; ++m) {
            float4 t = vP4[r][j + m];
            fp[4 * m] = t.x; fp[4 * m + 1] = t.y; fp[4 * m + 2] = t.z; fp[4 * m + 3] = t.w;
        }
#pragma unroll
        for (int o = 0; o < 4; ++o) {
            float mu1 = 0.f, mu2 = 0.f, sp = 0.f;
#pragma unroll
            for (int k = 0; k < KW; ++k) {
                mu1 += w[k] * fa[3 + o + k];
                mu2 += w[k] * fb[3 + o + k];
                sp  += w[k] * fp[3 + o + k];
            }
            float m12 = mu1 * mu2;
            float sigma = sp - m12;
            float sq = mu1 * mu1 + mu2 * mu2;
            float num = (2.f * m12 + C1F) * (2.f * sigma + C2F);
            float den = (sq + C1F) * (sq + C2F);
            acc += num / den;
        }
    }

    // ---- Reduce: wave shuffle -> LDS -> one atomic per block ----
#pragma unroll
    for (int off = 32; off > 0; off >>= 1)
        acc += __shfl_down(acc, off, 64);
    int wid = tid >> 6;
    int lane = tid & 63;
    if (lane == 0) wpart[wid] = acc;
    __syncthreads();
    if (tid == 0) {
        float s = (wpart[0] + wpart[1]) + (wpart[2] + wpart[3]);
        atomicAdd(out, s * inv_total);
    }
}

extern "C" void kernel_launch(void* const* d_in, const int* in_sizes, int n_in,
                              void* d_out, int out_size, void* d_ws, size_t ws_size,
                              hipStream_t stream) {
    const float* A = (const float*)d_in[0];
    const float* B = (const float*)d_in[1];
    float* out = (float*)d_out;

    const int total = in_sizes[0];                 // 32*1*512*512
    const int nimg = total / (IMG_H * IMG_W);      // 32

    hipMemsetAsync(d_out, 0, sizeof(float), stream);

    dim3 grid(IMG_W / TW, IMG_H / TH, nimg);       // (8, 32, 32) = 8192 blocks
    ssim_fused_kernel<<<grid, 256, 0, stream>>>(A, B, out, 1.0f / (float)total);
}